// Round 9
// baseline (222.795 us; speedup 1.0000x reference)
//
#include <hip/hip_runtime.h>
#include <hip/hip_bf16.h>

#define E_DIM 768
#define H_DIM 64
#define B_SZ 8
#define T_SZ 4096
#define BT (B_SZ * T_SZ)   // 32768

typedef __attribute__((ext_vector_type(8))) short short8;   // 8 bf16 (MFMA A/B frag, K=32)
typedef __attribute__((ext_vector_type(4))) short bf16x4;   // 4 bf16 (MFMA A/B frag, K=16)
typedef __attribute__((ext_vector_type(4))) float floatx4;  // MFMA C/D frag

// raw barrier: LDS visibility only — does NOT drain vmcnt (prefetch stays in flight)
#define RAWBAR() __asm__ volatile("s_waitcnt lgkmcnt(0)\n\ts_barrier" ::: "memory")

static __device__ __forceinline__ unsigned short bf1(float a) {
    __hip_bfloat16 h = __float2bfloat16(a);
    unsigned short u; __builtin_memcpy(&u, &h, 2); return u;
}
static __device__ __forceinline__ unsigned int pk2(float a, float b) {
    __hip_bfloat162 h = __float22bfloat162_rn(float2{a, b});
    unsigned int u; __builtin_memcpy(&u, &h, 4); return u;
}

// ---------------- W transpose + bf16: Wt[n][k], n = nt*64+nn ----------------
// Wq additionally scaled by log2(e) so attention softmax can use exp2 directly.
__global__ __launch_bounds__(256) void prep_w(
    const float* __restrict__ Wq, const float* __restrict__ Wk,
    const float* __restrict__ Wv, unsigned short* __restrict__ Wt)
{
    __shared__ float Ls[64][65];
    const int nt = blockIdx.x;           // 0..2
    const int kc = blockIdx.y;           // 0..11 (64-k chunk)
    const float* __restrict__ W = (nt == 0) ? Wq : (nt == 1) ? Wk : Wv;
    const float scl = (nt == 0) ? 1.44269504088896f : 1.0f;
    const int t = threadIdx.x;
    const int k0 = kc * 64;

#pragma unroll
    for (int it = 0; it < 16; ++it) {
        const int kk = (t >> 6) + it * 4;
        Ls[kk][t & 63] = W[(size_t)(k0 + kk) * H_DIM + (t & 63)];
    }
    __syncthreads();

#pragma unroll
    for (int it = 0; it < 4; ++it) {
        const int nl = (t >> 4) + it * 16;
        const int kl = (t & 15) * 4;
        unsigned int u[2];
        u[0] = pk2(Ls[kl + 0][nl] * scl, Ls[kl + 1][nl] * scl);
        u[1] = pk2(Ls[kl + 2][nl] * scl, Ls[kl + 3][nl] * scl);
        *(uint2*)(Wt + (size_t)(nt * 64 + nl) * E_DIM + k0 + kl) = *(uint2*)u;
    }
}

// ---------------- projection: W-in-registers, X double-buffered in LDS ----------------
// grid 256 (128-row m-tiles), 768 threads = 12 waves; wave w owns n-tile w (Q:0-3, K:4-7, V:8-11).
// NOTE: 96-VGPR persistent W file => 1 block/CU is the only viable occupancy.
// Do NOT add a min-waves launch_bounds clause: (768,6) capped VGPRs at ~85 and
// spilled the W file to scratch (FETCH 238 MB, 140 us — round-1 regression).
// Fitted cross-round budget: proj ~29.5 us vs ~16-20 us HBM floor — near-optimal; left alone.
__global__ __launch_bounds__(768) void proj_mfma(
    const float* __restrict__ X, const unsigned short* __restrict__ Wt,
    unsigned short* __restrict__ Qb, unsigned short* __restrict__ Kb,
    unsigned short* __restrict__ Vtb)
{
    __shared__ unsigned short Xs[2][16][776];   // 16-row X tile bf16, pad 776

    const int tid  = threadIdx.x;
    const int wave = tid >> 6, lane = tid & 63;
    const int row  = lane & 15, quad = lane >> 4;
    const int m0   = blockIdx.x * 128;

    // W prologue: 24 B-frags resident in registers (96 VGPRs)
    short8 bfr[24];
    {
        const unsigned short* wp = Wt + (size_t)(wave * 16 + row) * E_DIM + quad * 8;
#pragma unroll
        for (int ks = 0; ks < 24; ++ks) bfr[ks] = *(const short8*)(wp + ks * 32);
    }

    const int srow = tid & 15;
    const int sc   = tid >> 4;
    const float* __restrict__ xbase = X + (size_t)(m0 + srow) * E_DIM + sc * 16;

    float4 fx[4];
#define LDX(mt)                                                               \
    {                                                                         \
        const float* p = xbase + (size_t)(mt) * 16 * E_DIM;                   \
        fx[0] = *(const float4*)(p);     fx[1] = *(const float4*)(p + 4);     \
        fx[2] = *(const float4*)(p + 8); fx[3] = *(const float4*)(p + 12);    \
    }
#define STX(buf)                                                              \
    {                                                                         \
        unsigned int tmp[8];                                                  \
        tmp[0] = pk2(fx[0].x, fx[0].y); tmp[1] = pk2(fx[0].z, fx[0].w);       \
        tmp[2] = pk2(fx[1].x, fx[1].y); tmp[3] = pk2(fx[1].z, fx[1].w);       \
        tmp[4] = pk2(fx[2].x, fx[2].y); tmp[5] = pk2(fx[2].z, fx[2].w);       \
        tmp[6] = pk2(fx[3].x, fx[3].y); tmp[7] = pk2(fx[3].z, fx[3].w);       \
        *(int4*)&Xs[buf][srow][sc * 16]     = *(int4*)&tmp[0];                \
        *(int4*)&Xs[buf][srow][sc * 16 + 8] = *(int4*)&tmp[4];                \
    }

    // prologue: buf0 = tile 0; tile 1 loads in flight
    LDX(0); STX(0); LDX(1);
    RAWBAR();

    const int g  = wave >> 2;            // 0=Q, 1=K, 2=V
    const int h  = (wave & 3) * 16 + row;
    unsigned short* __restrict__ OQK = (g == 0) ? Qb : Kb;
    const int bb = m0 >> 12;

    int cur = 0;
    for (int mt = 0; mt < 8; ++mt) {
        // stage tile mt+1 into the idle buffer (safe: last reads of that buffer were
        // in window mt-1, sealed by the barrier), then issue loads for tile mt+2.
        if (mt < 7) STX(cur ^ 1);
        if (mt < 6) LDX(mt + 2);

        // 4 independent accumulator chains (MFMA dep-latency hiding at 3 waves/SIMD)
        floatx4 a0 = (floatx4)0.0f, a1 = (floatx4)0.0f;
        floatx4 a2 = (floatx4)0.0f, a3 = (floatx4)0.0f;
#pragma unroll
        for (int ks = 0; ks < 6; ++ks) {
            const short8 f0 = *(const short8*)&Xs[cur][row][(ks * 4 + 0) * 32 + quad * 8];
            const short8 f1 = *(const short8*)&Xs[cur][row][(ks * 4 + 1) * 32 + quad * 8];
            const short8 f2 = *(const short8*)&Xs[cur][row][(ks * 4 + 2) * 32 + quad * 8];
            const short8 f3 = *(const short8*)&Xs[cur][row][(ks * 4 + 3) * 32 + quad * 8];
            a0 = __builtin_amdgcn_mfma_f32_16x16x32_bf16(f0, bfr[ks * 4 + 0], a0, 0, 0, 0);
            a1 = __builtin_amdgcn_mfma_f32_16x16x32_bf16(f1, bfr[ks * 4 + 1], a1, 0, 0, 0);
            a2 = __builtin_amdgcn_mfma_f32_16x16x32_bf16(f2, bfr[ks * 4 + 2], a2, 0, 0, 0);
            a3 = __builtin_amdgcn_mfma_f32_16x16x32_bf16(f3, bfr[ks * 4 + 3], a3, 0, 0, 0);
        }
        floatx4 acc;
#pragma unroll
        for (int r = 0; r < 4; ++r) acc[r] = (a0[r] + a1[r]) + (a2[r] + a3[r]);

        const int mr = m0 + mt * 16 + quad * 4;
        if (g < 2) {
#pragma unroll
            for (int r = 0; r < 4; ++r)
                OQK[(size_t)(mr + r) * H_DIM + h] = bf1(acc[r]);
        } else {
            const int t0 = mr & 4095;
            unsigned int u[2];
            u[0] = pk2(acc[0], acc[1]); u[1] = pk2(acc[2], acc[3]);
            *(uint2*)(Vtb + ((size_t)bb * H_DIM + h) * T_SZ + t0) = *(uint2*)u;
        }

        RAWBAR();
        cur ^= 1;
    }
#undef LDX
#undef STX
}

// ---------------- flash attention v8: 2-wave blocks, 32-key tiles ----------------
// Round-6 lesson extended: barrier-domain granularity is the lever. Per-wave patch
// (16q x 32k) and all per-iter content are IDENTICAL to v7; but blocks are now
// 2 waves / 32-row q-tile / 32-key tiles: barriers sync only 2 waves, LDS = 9.7 KB
// -> 12 blocks/CU (vs 6). Each wave owns complete O rows (no key-split within
// block) => the Oc LDS-transpose combine + lc + 2 syncthreads are DELETED.
// Chunks of <=24 tiles; no-max softmax => chunk partials additive (global combine).
__global__ __launch_bounds__(128, 6) void attn_mfma(
    const unsigned short* __restrict__ Qb,
    const unsigned short* __restrict__ Kb,
    const unsigned short* __restrict__ Vtb,
    float* __restrict__ Opart, float* __restrict__ lpart,
    float* __restrict__ Out)
{
    __shared__ __align__(16) unsigned short Ks[32][72];   // K tile [key][h], 4608 B
    __shared__ __align__(16) unsigned short Vs[64][40];   // V^T tile [h][key], 5120 B

    const int lb = blockIdx.x;
    const int b  = lb & 7;                     // batch -> XCD (L2 locality)
    const int s  = lb >> 3;                    // 0..407, LPT-ordered (heavy chunks first)
    int qq, c, m;
    if (s < 48)       { m = 6; qq = 127 - s / 6;                      c = s % 6; }
    else if (s < 168) { m = 5; const int i = s - 48;  qq = 119 - i / 5;  c = i % 5; }
    else if (s < 264) { m = 4; const int i = s - 168; qq = 95 - (i >> 2); c = i & 3; }
    else if (s < 336) { m = 3; const int i = s - 264; qq = 71 - i / 3;   c = i % 3; }
    else if (s < 384) { m = 2; const int i = s - 336; qq = 47 - (i >> 1); c = i & 1; }
    else              { m = 1; qq = 407 - s; c = 0; }
    const int ntot = qq + 1;                   // 32-key tiles for this q-tile (causal)
    const int k0t  = (c * ntot) / m;
    const int k1t  = ((c + 1) * ntot) / m;
    const int ktd  = ntot - 1;                 // diagonal tile (global index)
    const int n    = k1t - k0t;                // 1..24
    const bool split = (m > 1);

    const int tid  = threadIdx.x;
    const int wq   = tid >> 6;                 // wave = q-half (rows wq*16..)
    const int lane = tid & 63;
    const int col  = lane & 15, quad = lane >> 4;

    const size_t base = (size_t)b * T_SZ * H_DIM;
    const int q0  = qq * 32;

    // Q fragments: lane holds Q[q=col][h=quad*8..], the 16x16x32 B-operand
    short8 qf0, qf1;
    {
        const unsigned short* qp = Qb + base + (size_t)(q0 + wq * 16 + col) * H_DIM + quad * 8;
        qf0 = *(const short8*)(qp);
        qf1 = *(const short8*)(qp + 32);
    }

    floatx4 o[4];
#pragma unroll
    for (int i = 0; i < 4; ++i) o[i] = (floatx4)0.0f;
    float lp = 0.0f;                           // per-lane denom partial (q=col)

    // cooperative staging (128 threads): K 4KB (32B/thread), V^T 4KB (32B/thread)
    const int krow = tid >> 2, kcol = (tid & 3) * 16;   // K: 32 rows x 4 chunks
    const int vrow = tid >> 1, vcol = (tid & 1) * 16;   // V^T: 64 rows x 2 chunks
    const unsigned short* __restrict__ Ksrc = Kb + base + (size_t)krow * H_DIM + kcol;
    const unsigned short* __restrict__ Vsrc = Vtb + ((size_t)b * H_DIM + vrow) * T_SZ + vcol;

    int4 kr0, kr1, vr0, vr1;
#define LDKV(t)                                                          \
    {                                                                    \
        const unsigned short* kp = Ksrc + (size_t)(t) * 32 * H_DIM;      \
        kr0 = *(const int4*)kp; kr1 = *(const int4*)(kp + 8);            \
        const unsigned short* vp = Vsrc + (t) * 32;                      \
        vr0 = *(const int4*)vp; vr1 = *(const int4*)(vp + 8);            \
    }
#define STKV()                                                           \
    {                                                                    \
        *(int4*)&Ks[krow][kcol] = kr0; *(int4*)&Ks[krow][kcol + 8] = kr1; \
        *(int4*)&Vs[vrow][vcol] = vr0; *(int4*)&Vs[vrow][vcol + 8] = vr1; \
    }

    LDKV(k0t);
    STKV();
    if (n > 1) LDKV(k0t + 1);
    RAWBAR();

    for (int i = 0; i < n; ++i) {
        const int kt = k0t + i;

        // S^T = K Q^T on this wave's 32k x 16q patch: A = K rows (keys), B = Q.
        // sv[j][r] = S[q = col][key = j*16 + quad*4 + r]
        floatx4 sv[2];
        __builtin_amdgcn_s_setprio(1);
#pragma unroll
        for (int j = 0; j < 2; ++j) {
            const unsigned short* kp = &Ks[j * 16 + col][quad * 8];
            floatx4 a = (floatx4)0.0f;
            a = __builtin_amdgcn_mfma_f32_16x16x32_bf16(*(const short8*)(kp),      qf0, a, 0, 0, 0);
            a = __builtin_amdgcn_mfma_f32_16x16x32_bf16(*(const short8*)(kp + 32), qf1, a, 0, 0, 0);
            sv[j] = a;
        }
        __builtin_amdgcn_s_setprio(0);

        if (kt == ktd) {                       // causal mask on diagonal tile
            const int qg = q0 + wq * 16 + col;
#pragma unroll
            for (int j = 0; j < 2; ++j) {
                const int kb0 = kt * 32 + j * 16 + quad * 4;
#pragma unroll
                for (int r = 0; r < 4; ++r)
                    if (kb0 + r > qg) sv[j][r] = -1e30f;
            }
        }

        // no-max softmax (Q pre-scaled by log2e): p = exp2(s); P stays in registers.
        bf16x4 pa[2];
#pragma unroll
        for (int j = 0; j < 2; ++j) {
            float p0 = exp2f(sv[j][0]);
            float p1 = exp2f(sv[j][1]);
            float p2 = exp2f(sv[j][2]);
            float p3 = exp2f(sv[j][3]);
            lp += (p0 + p1) + (p2 + p3);
            unsigned int u0, u1;
            __asm__("v_cvt_pk_bf16_f32 %0, %1, %2" : "=v"(u0) : "v"(p0), "v"(p1));
            __asm__("v_cvt_pk_bf16_f32 %0, %1, %2" : "=v"(u1) : "v"(p2), "v"(p3));
            union { unsigned int u[2]; bf16x4 v; } pu;
            pu.u[0] = u0; pu.u[1] = u1;
            pa[j] = pu.v;
        }

        // O += P V: 8x K=16 MFMA, A = pa (registers), B = V^T 4-key slices (b64 LDS reads)
        __builtin_amdgcn_s_setprio(1);
#pragma unroll
        for (int d = 0; d < 4; ++d) {
#pragma unroll
            for (int j = 0; j < 2; ++j) {
                const bf16x4 vb = *(const bf16x4*)(&Vs[d * 16 + col][j * 16 + quad * 4]);
                o[d] = __builtin_amdgcn_mfma_f32_16x16x16bf16_1k(pa[j], vb, o[d], 0, 0, 0);
            }
        }
        __builtin_amdgcn_s_setprio(0);

        RAWBAR();                              // both waves done reading Ks/Vs
        if (i + 1 < n) {
            STKV();                            // vmcnt wait: loads issued a full iter ago
            if (i + 2 < n) LDKV(kt + 2);
        }
        RAWBAR();
    }

    // denom: reduce lp across the 4 quads (same col); then fetch per-o-row values.
    lp += __shfl_xor(lp, 16);
    lp += __shfl_xor(lp, 32);
    // o[d][r] covers q-row quad*4+r; lane quad*4+r holds l[q=quad*4+r] (its col field).
    float lr[4];
#pragma unroll
    for (int r = 0; r < 4; ++r) lr[r] = __shfl(lp, quad * 4 + r);

    if (!split) {
        float* op = Out + base + (size_t)(q0 + wq * 16 + quad * 4) * H_DIM;
#pragma unroll
        for (int r = 0; r < 4; ++r) {
            const float inv = 1.0f / lr[r];
#pragma unroll
            for (int d = 0; d < 4; ++d)
                op[(size_t)r * H_DIM + d * 16 + col] = o[d][r] * inv;
        }
    } else {
        const int pidx = (b * 128 + qq) * 6 + c;
        float* op = Opart + ((size_t)pidx * 32 + wq * 16 + quad * 4) * 64;
#pragma unroll
        for (int r = 0; r < 4; ++r)
#pragma unroll
            for (int d = 0; d < 4; ++d)
                op[(size_t)r * 64 + d * 16 + col] = o[d][r];
        if (quad == 0) lpart[pidx * 32 + wq * 16 + col] = lp;
    }
#undef LDKV
#undef STKV
}

// ---------------- split-K combine: q-tiles qq>=24, m in {2..6} partials ----------------
__global__ __launch_bounds__(256) void attn_combine(
    const float* __restrict__ Opart, const float* __restrict__ lpart,
    float* __restrict__ Out)
{
    const int qq  = 24 + blockIdx.x;          // 24..127
    const int b   = blockIdx.y;               // 0..7
    const int m   = (qq + 24) / 24;           // ceil((qq+1)/24) in 2..6
    const int tid = threadIdx.x;
    const int orow = tid >> 3;                // 0..31
    const int d0   = (tid & 7) * 8;
    const int p0   = (b * 128 + qq) * 6;

    float4 a0 = {0.f, 0.f, 0.f, 0.f}, a1 = {0.f, 0.f, 0.f, 0.f};
    float l = 0.0f;
    for (int j = 0; j < m; ++j) {
        const float* P = Opart + ((size_t)(p0 + j) * 32 + orow) * 64 + d0;
        const float4 b0 = *(const float4*)(P);
        const float4 b1 = *(const float4*)(P + 4);
        a0.x += b0.x; a0.y += b0.y; a0.z += b0.z; a0.w += b0.w;
        a1.x += b1.x; a1.y += b1.y; a1.z += b1.z; a1.w += b1.w;
        l += lpart[(p0 + j) * 32 + orow];
    }
    const float inv = 1.0f / l;
    a0.x *= inv; a0.y *= inv; a0.z *= inv; a0.w *= inv;
    a1.x *= inv; a1.y *= inv; a1.z *= inv; a1.w *= inv;

    float* op = Out + ((size_t)b * T_SZ + qq * 32 + orow) * H_DIM + d0;
    *(float4*)(op)     = a0;
    *(float4*)(op + 4) = a1;
}

extern "C" void kernel_launch(void* const* d_in, const int* in_sizes, int n_in,
                              void* d_out, int out_size, void* d_ws, size_t ws_size,
                              hipStream_t stream) {
    const float* X  = (const float*)d_in[0];
    const float* Wq = (const float*)d_in[1];
    const float* Wk = (const float*)d_in[2];
    const float* Wv = (const float*)d_in[3];

    unsigned short* Wt  = (unsigned short*)d_ws;            // 192*768 bf16
    unsigned short* Qb  = Wt + (size_t)192 * E_DIM;
    unsigned short* Kb  = Qb + (size_t)BT * H_DIM;
    unsigned short* Vtb = Kb + (size_t)BT * H_DIM;          // V transposed [b][h][t]
    float* Opart = (float*)(Vtb + (size_t)BT * H_DIM);      // [6144][32][64] f32 = 50.3 MB
    float* lpart = Opart + (size_t)6144 * 32 * 64;          // [6144][32] f32

    prep_w<<<dim3(3, 12), 256, 0, stream>>>(Wq, Wk, Wv, Wt);
    proj_mfma<<<256, 768, 0, stream>>>(X, Wt, Qb, Kb, Vtb);
    attn_mfma<<<3264, 128, 0, stream>>>(Qb, Kb, Vtb, Opart, lpart, (float*)d_out);
    attn_combine<<<dim3(104, 8), 256, 0, stream>>>(Opart, lpart, (float*)d_out);
}

// Round 10
// 214.138 us; speedup vs baseline: 1.0404x; 1.0404x over previous
//
#include <hip/hip_runtime.h>
#include <hip/hip_bf16.h>

#define E_DIM 768
#define H_DIM 64
#define B_SZ 8
#define T_SZ 4096
#define BT (B_SZ * T_SZ)   // 32768

typedef __attribute__((ext_vector_type(8))) short short8;   // 8 bf16 (MFMA A/B frag, K=32)
typedef __attribute__((ext_vector_type(4))) float floatx4;  // MFMA C/D frag

// raw barrier: LDS visibility only — does NOT drain vmcnt (prefetch stays in flight)
#define RAWBAR() __asm__ volatile("s_waitcnt lgkmcnt(0)\n\ts_barrier" ::: "memory")

static __device__ __forceinline__ unsigned short bf1(float a) {
    __hip_bfloat16 h = __float2bfloat16(a);
    unsigned short u; __builtin_memcpy(&u, &h, 2); return u;
}
static __device__ __forceinline__ unsigned int pk2(float a, float b) {
    __hip_bfloat162 h = __float22bfloat162_rn(float2{a, b});
    unsigned int u; __builtin_memcpy(&u, &h, 4); return u;
}

// ---------------- W transpose + bf16: Wt[n][k], n = nt*64+nn ----------------
// Wq additionally scaled by log2(e) so attention softmax can use exp2 directly.
__global__ __launch_bounds__(256) void prep_w(
    const float* __restrict__ Wq, const float* __restrict__ Wk,
    const float* __restrict__ Wv, unsigned short* __restrict__ Wt)
{
    __shared__ float Ls[64][65];
    const int nt = blockIdx.x;           // 0..2
    const int kc = blockIdx.y;           // 0..11 (64-k chunk)
    const float* __restrict__ W = (nt == 0) ? Wq : (nt == 1) ? Wk : Wv;
    const float scl = (nt == 0) ? 1.44269504088896f : 1.0f;
    const int t = threadIdx.x;
    const int k0 = kc * 64;

#pragma unroll
    for (int it = 0; it < 16; ++it) {
        const int kk = (t >> 6) + it * 4;
        Ls[kk][t & 63] = W[(size_t)(k0 + kk) * H_DIM + (t & 63)];
    }
    __syncthreads();

#pragma unroll
    for (int it = 0; it < 4; ++it) {
        const int nl = (t >> 4) + it * 16;
        const int kl = (t & 15) * 4;
        unsigned int u[2];
        u[0] = pk2(Ls[kl + 0][nl] * scl, Ls[kl + 1][nl] * scl);
        u[1] = pk2(Ls[kl + 2][nl] * scl, Ls[kl + 3][nl] * scl);
        *(uint2*)(Wt + (size_t)(nt * 64 + nl) * E_DIM + k0 + kl) = *(uint2*)u;
    }
}

// ---------------- projection: W-in-registers, X double-buffered in LDS ----------------
// grid 256 (128-row m-tiles), 768 threads = 12 waves; wave w owns n-tile w (Q:0-3, K:4-7, V:8-11).
// NOTE: 96-VGPR persistent W file => 1 block/CU is the only viable occupancy.
// Do NOT add a min-waves launch_bounds clause: (768,6) capped VGPRs at ~85 and
// spilled the W file to scratch (FETCH 238 MB, 140 us — round-1 regression).
// Fitted cross-round budget: proj ~29.5 us vs ~16-20 us HBM floor — near-optimal; left alone.
__global__ __launch_bounds__(768) void proj_mfma(
    const float* __restrict__ X, const unsigned short* __restrict__ Wt,
    unsigned short* __restrict__ Qb, unsigned short* __restrict__ Kb,
    unsigned short* __restrict__ Vtb)
{
    __shared__ unsigned short Xs[2][16][776];   // 16-row X tile bf16, pad 776

    const int tid  = threadIdx.x;
    const int wave = tid >> 6, lane = tid & 63;
    const int row  = lane & 15, quad = lane >> 4;
    const int m0   = blockIdx.x * 128;

    // W prologue: 24 B-frags resident in registers (96 VGPRs)
    short8 bfr[24];
    {
        const unsigned short* wp = Wt + (size_t)(wave * 16 + row) * E_DIM + quad * 8;
#pragma unroll
        for (int ks = 0; ks < 24; ++ks) bfr[ks] = *(const short8*)(wp + ks * 32);
    }

    const int srow = tid & 15;
    const int sc   = tid >> 4;
    const float* __restrict__ xbase = X + (size_t)(m0 + srow) * E_DIM + sc * 16;

    float4 fx[4];
#define LDX(mt)                                                               \
    {                                                                         \
        const float* p = xbase + (size_t)(mt) * 16 * E_DIM;                   \
        fx[0] = *(const float4*)(p);     fx[1] = *(const float4*)(p + 4);     \
        fx[2] = *(const float4*)(p + 8); fx[3] = *(const float4*)(p + 12);    \
    }
#define STX(buf)                                                              \
    {                                                                         \
        unsigned int tmp[8];                                                  \
        tmp[0] = pk2(fx[0].x, fx[0].y); tmp[1] = pk2(fx[0].z, fx[0].w);       \
        tmp[2] = pk2(fx[1].x, fx[1].y); tmp[3] = pk2(fx[1].z, fx[1].w);       \
        tmp[4] = pk2(fx[2].x, fx[2].y); tmp[5] = pk2(fx[2].z, fx[2].w);       \
        tmp[6] = pk2(fx[3].x, fx[3].y); tmp[7] = pk2(fx[3].z, fx[3].w);       \
        *(int4*)&Xs[buf][srow][sc * 16]     = *(int4*)&tmp[0];                \
        *(int4*)&Xs[buf][srow][sc * 16 + 8] = *(int4*)&tmp[4];                \
    }

    // prologue: buf0 = tile 0; tile 1 loads in flight
    LDX(0); STX(0); LDX(1);
    RAWBAR();

    const int g  = wave >> 2;            // 0=Q, 1=K, 2=V
    const int h  = (wave & 3) * 16 + row;
    unsigned short* __restrict__ OQK = (g == 0) ? Qb : Kb;
    const int bb = m0 >> 12;

    int cur = 0;
    for (int mt = 0; mt < 8; ++mt) {
        // stage tile mt+1 into the idle buffer (safe: last reads of that buffer were
        // in window mt-1, sealed by the barrier), then issue loads for tile mt+2.
        if (mt < 7) STX(cur ^ 1);
        if (mt < 6) LDX(mt + 2);

        // 4 independent accumulator chains (MFMA dep-latency hiding at 3 waves/SIMD)
        floatx4 a0 = (floatx4)0.0f, a1 = (floatx4)0.0f;
        floatx4 a2 = (floatx4)0.0f, a3 = (floatx4)0.0f;
#pragma unroll
        for (int ks = 0; ks < 6; ++ks) {
            const short8 f0 = *(const short8*)&Xs[cur][row][(ks * 4 + 0) * 32 + quad * 8];
            const short8 f1 = *(const short8*)&Xs[cur][row][(ks * 4 + 1) * 32 + quad * 8];
            const short8 f2 = *(const short8*)&Xs[cur][row][(ks * 4 + 2) * 32 + quad * 8];
            const short8 f3 = *(const short8*)&Xs[cur][row][(ks * 4 + 3) * 32 + quad * 8];
            a0 = __builtin_amdgcn_mfma_f32_16x16x32_bf16(f0, bfr[ks * 4 + 0], a0, 0, 0, 0);
            a1 = __builtin_amdgcn_mfma_f32_16x16x32_bf16(f1, bfr[ks * 4 + 1], a1, 0, 0, 0);
            a2 = __builtin_amdgcn_mfma_f32_16x16x32_bf16(f2, bfr[ks * 4 + 2], a2, 0, 0, 0);
            a3 = __builtin_amdgcn_mfma_f32_16x16x32_bf16(f3, bfr[ks * 4 + 3], a3, 0, 0, 0);
        }
        floatx4 acc;
#pragma unroll
        for (int r = 0; r < 4; ++r) acc[r] = (a0[r] + a1[r]) + (a2[r] + a3[r]);

        const int mr = m0 + mt * 16 + quad * 4;
        if (g < 2) {
#pragma unroll
            for (int r = 0; r < 4; ++r)
                OQK[(size_t)(mr + r) * H_DIM + h] = bf1(acc[r]);
        } else {
            const int t0 = mr & 4095;
            unsigned int u[2];
            u[0] = pk2(acc[0], acc[1]); u[1] = pk2(acc[2], acc[3]);
            *(uint2*)(Vtb + ((size_t)bb * H_DIM + h) * T_SZ + t0) = *(uint2*)u;
        }

        RAWBAR();
        cur ^= 1;
    }
#undef LDX
#undef STX
}

// ---------------- flash attention v9: v7 structure + permuted-K => K=32 PV ----------------
// K staged into LDS with permuted rows: LDS row (wk, j, m) holds key wk*32 + 8*(m>>2) + 4j + (m&3).
// The two QK^T MFMAs per j then give lane (col,quad) P for keys quad*8..quad*8+7 — exactly the
// 16x16x32 A-frag. PV collapses from 8 K=16 MFMAs + 8 b64 reads to 4 K=32 MFMAs + 4 b128 reads.
// Everything else identical to v7 (best measured): 4-wave blocks, 64-key tiles, <=16-tile chunks,
// single 18.4 KB buffer, 2 raw barriers/iter, (256,6). No-max softmax partials additive.
__global__ __launch_bounds__(256, 6) void attn_mfma(
    const unsigned short* __restrict__ Qb,
    const unsigned short* __restrict__ Kb,
    const unsigned short* __restrict__ Vtb,
    float* __restrict__ Opart, float* __restrict__ lpart,
    float* __restrict__ Out)
{
    // KV[0] = permuted K tile, KV[1] = V^T tile [h][key]; aliased as Oc (float) for combine
    __shared__ __align__(16) unsigned short KV[2][64][72];   // 18432 B
    __shared__ float lc[4][16];

    const int lb = blockIdx.x;
    const int b  = lb & 7;                     // batch -> XCD (L2 locality)
    const int s  = lb >> 3;                    // 0..319, LPT-ordered (heavy chunks first)
    int qq, c, m;
    if (s < 128)      { m = 4; qq = 96 + (s >> 2); c = s & 3; }
    else if (s < 224) { m = 3; const int t = s - 128; const int t3 = t / 3; qq = 64 + t3; c = t - t3 * 3; }
    else if (s < 288) { m = 2; const int t = s - 224; qq = 32 + (t >> 1); c = t & 1; }
    else              { m = 1; qq = s - 288; c = 0; }
    const int ntot = (qq >> 1) + 1;            // total 64-key tiles for this q-tile
    const int k0t  = (c * ntot) / m;
    const int k1t  = ((c + 1) * ntot) / m;
    const int ktd  = ntot - 1;                 // diagonal tile (global index)
    const int n    = k1t - k0t;                // 1..16
    const bool split = (m > 1);

    const int tid  = threadIdx.x;
    const int wave = tid >> 6, lane = tid & 63;
    const int col  = lane & 15, quad = lane >> 4;
    const int wq   = wave >> 1;                // q-half (rows wq*16..)
    const int wk   = wave & 1;                 // key-half (keys wk*32..)

    const size_t base = (size_t)b * T_SZ * H_DIM;
    const int q0  = qq * 32;

    // Q fragments: lane holds Q[q=col][h=quad*8..], the 16x16x32 B-operand
    short8 qf0, qf1;
    {
        const unsigned short* qp = Qb + base + (size_t)(q0 + wq * 16 + col) * H_DIM + quad * 8;
        qf0 = *(const short8*)(qp);
        qf1 = *(const short8*)(qp + 32);
    }

    floatx4 o[4];
#pragma unroll
    for (int i = 0; i < 4; ++i) o[i] = (floatx4)0.0f;
    float lp = 0.0f;                           // per-lane denom partial (q=col)

    // cooperative staging: 32B of K + 32B of V^T per thread per tile (coalesced reads).
    // K LDS row is PERMUTED: key krow -> row (krow>>5)*32 + ((krow>>2)&1)*16
    //                                       + ((krow&31)>>3)*4 + (krow&3)
    const int krow = tid >> 2, kcol = (tid & 3) * 16;
    const int kprow = (krow & 32) + ((krow >> 2) & 1) * 16 + ((krow & 31) >> 3) * 4 + (krow & 3);
    const unsigned short* __restrict__ Ksrc = Kb + base + (size_t)krow * H_DIM + kcol;
    const unsigned short* __restrict__ Vsrc = Vtb + ((size_t)b * H_DIM + krow) * T_SZ + kcol;

    int4 kr0, kr1, vr0, vr1;
#define LDKV(t)                                                          \
    {                                                                    \
        const unsigned short* kp = Ksrc + (size_t)(t) * 64 * H_DIM;      \
        kr0 = *(const int4*)kp; kr1 = *(const int4*)(kp + 8);            \
        const unsigned short* vp = Vsrc + (t) * 64;                      \
        vr0 = *(const int4*)vp; vr1 = *(const int4*)(vp + 8);            \
    }
#define STKV()                                                           \
    {                                                                    \
        *(int4*)&KV[0][kprow][kcol] = kr0; *(int4*)&KV[0][kprow][kcol + 8] = kr1; \
        *(int4*)&KV[1][krow][kcol] = vr0; *(int4*)&KV[1][krow][kcol + 8] = vr1; \
    }

    LDKV(k0t);
    STKV();
    if (n > 1) LDKV(k0t + 1);
    RAWBAR();

    for (int i = 0; i < n; ++i) {
        const int kt = k0t + i;

        // S^T = K Q^T, A = permuted K rows, B = Q. After the permutation,
        // a0[r] = S[q=col][key-local = quad*8 + r], a1[r] = ... + 4 + r.
        floatx4 a0 = (floatx4)0.0f, a1 = (floatx4)0.0f;
        __builtin_amdgcn_s_setprio(1);
        {
            const unsigned short* kp0 = &KV[0][wk * 32 + col][quad * 8];        // j=0
            const unsigned short* kp1 = &KV[0][wk * 32 + 16 + col][quad * 8];   // j=1
            a0 = __builtin_amdgcn_mfma_f32_16x16x32_bf16(*(const short8*)(kp0),      qf0, a0, 0, 0, 0);
            a1 = __builtin_amdgcn_mfma_f32_16x16x32_bf16(*(const short8*)(kp1),      qf0, a1, 0, 0, 0);
            a0 = __builtin_amdgcn_mfma_f32_16x16x32_bf16(*(const short8*)(kp0 + 32), qf1, a0, 0, 0, 0);
            a1 = __builtin_amdgcn_mfma_f32_16x16x32_bf16(*(const short8*)(kp1 + 32), qf1, a1, 0, 0, 0);
        }
        __builtin_amdgcn_s_setprio(0);

        if (kt == ktd) {                       // causal mask on diagonal tile
            const int qg = q0 + wq * 16 + col;
            const int kb = kt * 64 + wk * 32 + quad * 8;
#pragma unroll
            for (int r = 0; r < 4; ++r) {
                if (kb + r > qg)     a0[r] = -1e30f;
                if (kb + 4 + r > qg) a1[r] = -1e30f;
            }
        }

        // no-max softmax (Q pre-scaled by log2e): p = exp2(s); P packs straight into
        // the 16x16x32 A-frag (keys quad*8..quad*8+7). Masked -1e30 -> exp2 -> 0.
        const float p0 = exp2f(a0[0]), p1 = exp2f(a0[1]), p2 = exp2f(a0[2]), p3 = exp2f(a0[3]);
        const float p4 = exp2f(a1[0]), p5 = exp2f(a1[1]), p6 = exp2f(a1[2]), p7 = exp2f(a1[3]);
        lp += ((p0 + p1) + (p2 + p3)) + ((p4 + p5) + (p6 + p7));
        unsigned int u0, u1, u2, u3;
        __asm__("v_cvt_pk_bf16_f32 %0, %1, %2" : "=v"(u0) : "v"(p0), "v"(p1));
        __asm__("v_cvt_pk_bf16_f32 %0, %1, %2" : "=v"(u1) : "v"(p2), "v"(p3));
        __asm__("v_cvt_pk_bf16_f32 %0, %1, %2" : "=v"(u2) : "v"(p4), "v"(p5));
        __asm__("v_cvt_pk_bf16_f32 %0, %1, %2" : "=v"(u3) : "v"(p6), "v"(p7));
        union { unsigned int u[4]; short8 v; } pu;
        pu.u[0] = u0; pu.u[1] = u1; pu.u[2] = u2; pu.u[3] = u3;
        const short8 pa = pu.v;

        // O += P V: 4x K=32 MFMA, A = pa (registers), B = V^T b128 slices
        __builtin_amdgcn_s_setprio(1);
#pragma unroll
        for (int d = 0; d < 4; ++d) {
            const short8 vb = *(const short8*)(&KV[1][d * 16 + col][wk * 32 + quad * 8]);
            o[d] = __builtin_amdgcn_mfma_f32_16x16x32_bf16(pa, vb, o[d], 0, 0, 0);
        }
        __builtin_amdgcn_s_setprio(0);

        RAWBAR();                              // all waves done reading KV
        if (i + 1 < n) {
            STKV();                            // vmcnt wait: loads issued a full iter ago
            if (i + 2 < n) LDKV(kt + 2);
        }
        RAWBAR();
    }

    // denom: reduce lp across the 4 quads (same col) -> lc[wave][q-local]
    lp += __shfl_xor(lp, 16);
    lp += __shfl_xor(lp, 32);
    if (quad == 0) lc[wave][col] = lp;
    __syncthreads();                           // all waves done with KV; lc visible

    // O partials into the KV area (Oc[wave][q16][64])
    float* __restrict__ Oc = (float*)&KV[0][0][0];
#pragma unroll
    for (int r = 0; r < 4; ++r)
#pragma unroll
        for (int d = 0; d < 4; ++d)
            Oc[((wave * 16) + quad * 4 + r) * 64 + d * 16 + col] = o[d][r];
    __syncthreads();

    // combine: rows 0-15 <- waves 0+1, rows 16-31 <- waves 2+3
    {
        const int orow = tid >> 3;             // 0..31
        const int d0   = (tid & 7) * 8;        // 0..56
        const int rl   = orow & 15;
        const int wb   = (orow >> 4) * 2;
        const float* p0 = &Oc[((wb * 16) + rl) * 64 + d0];
        const float* p1 = &Oc[(((wb + 1) * 16) + rl) * 64 + d0];
        const float lsum = lc[wb][rl] + lc[wb + 1][rl];
        float4 a0 = *(const float4*)(p0);
        float4 a1 = *(const float4*)(p0 + 4);
        const float4 b0 = *(const float4*)(p1);
        const float4 b1 = *(const float4*)(p1 + 4);
        a0.x += b0.x; a0.y += b0.y; a0.z += b0.z; a0.w += b0.w;
        a1.x += b1.x; a1.y += b1.y; a1.z += b1.z; a1.w += b1.w;
        if (!split) {
            const float inv = 1.0f / lsum;
            a0.x *= inv; a0.y *= inv; a0.z *= inv; a0.w *= inv;
            a1.x *= inv; a1.y *= inv; a1.z *= inv; a1.w *= inv;
            float* op = Out + base + (size_t)(q0 + orow) * H_DIM + d0;
            *(float4*)(op)     = a0;
            *(float4*)(op + 4) = a1;
        } else {
            const int pidx = (b * 96 + (qq - 32)) * 4 + c;
            float* op = Opart + ((size_t)pidx * 32 + orow) * 64 + d0;
            *(float4*)(op)     = a0;
            *(float4*)(op + 4) = a1;
            if ((tid & 7) == 0) lpart[pidx * 32 + orow] = lsum;
        }
    }
#undef LDKV
#undef STKV
}

// ---------------- split-K combine: q-tiles qq>=32, m in {2,3,4} partials ----------------
__global__ __launch_bounds__(256) void attn_combine(
    const float* __restrict__ Opart, const float* __restrict__ lpart,
    float* __restrict__ Out)
{
    const int qi  = blockIdx.x;               // 0..95 (qq - 32)
    const int b   = blockIdx.y;               // 0..7
    const int qq  = 32 + qi;
    const int m   = (qq < 64) ? 2 : (qq < 96) ? 3 : 4;
    const int tid = threadIdx.x;
    const int orow = tid >> 3;                // 0..31
    const int d0   = (tid & 7) * 8;
    const int p0   = (b * 96 + qi) * 4;

    float4 a0 = {0.f, 0.f, 0.f, 0.f}, a1 = {0.f, 0.f, 0.f, 0.f};
    float l = 0.0f;
    for (int j = 0; j < m; ++j) {
        const float* P = Opart + ((size_t)(p0 + j) * 32 + orow) * 64 + d0;
        const float4 b0 = *(const float4*)(P);
        const float4 b1 = *(const float4*)(P + 4);
        a0.x += b0.x; a0.y += b0.y; a0.z += b0.z; a0.w += b0.w;
        a1.x += b1.x; a1.y += b1.y; a1.z += b1.z; a1.w += b1.w;
        l += lpart[(p0 + j) * 32 + orow];
    }
    const float inv = 1.0f / l;
    a0.x *= inv; a0.y *= inv; a0.z *= inv; a0.w *= inv;
    a1.x *= inv; a1.y *= inv; a1.z *= inv; a1.w *= inv;

    float* op = Out + ((size_t)b * T_SZ + qq * 32 + orow) * H_DIM + d0;
    *(float4*)(op)     = a0;
    *(float4*)(op + 4) = a1;
}

extern "C" void kernel_launch(void* const* d_in, const int* in_sizes, int n_in,
                              void* d_out, int out_size, void* d_ws, size_t ws_size,
                              hipStream_t stream) {
    const float* X  = (const float*)d_in[0];
    const float* Wq = (const float*)d_in[1];
    const float* Wk = (const float*)d_in[2];
    const float* Wv = (const float*)d_in[3];

    unsigned short* Wt  = (unsigned short*)d_ws;            // 192*768 bf16
    unsigned short* Qb  = Wt + (size_t)192 * E_DIM;
    unsigned short* Kb  = Qb + (size_t)BT * H_DIM;
    unsigned short* Vtb = Kb + (size_t)BT * H_DIM;          // V transposed [b][h][t]
    float* Opart = (float*)(Vtb + (size_t)BT * H_DIM);      // [3072][32][64] f32 = 25.2 MB
    float* lpart = Opart + (size_t)3072 * 32 * 64;          // [3072][32] f32

    prep_w<<<dim3(3, 12), 256, 0, stream>>>(Wq, Wk, Wv, Wt);
    proj_mfma<<<256, 768, 0, stream>>>(X, Wt, Qb, Kb, Vtb);
    attn_mfma<<<2560, 256, 0, stream>>>(Qb, Kb, Vtb, Opart, lpart, (float*)d_out);
    attn_combine<<<dim3(96, 8), 256, 0, stream>>>(Opart, lpart, (float*)d_out);
}

// Round 11
// 212.138 us; speedup vs baseline: 1.0502x; 1.0094x over previous
//
#include <hip/hip_runtime.h>
#include <hip/hip_bf16.h>

#define E_DIM 768
#define H_DIM 64
#define B_SZ 8
#define T_SZ 4096
#define BT (B_SZ * T_SZ)   // 32768

typedef __attribute__((ext_vector_type(8))) short short8;   // 8 bf16 (MFMA A/B frag, K=32)
typedef __attribute__((ext_vector_type(4))) float floatx4;  // MFMA C/D frag

// raw barrier: LDS visibility only — does NOT drain vmcnt (prefetch stays in flight)
#define RAWBAR() __asm__ volatile("s_waitcnt lgkmcnt(0)\n\ts_barrier" ::: "memory")

static __device__ __forceinline__ unsigned short bf1(float a) {
    __hip_bfloat16 h = __float2bfloat16(a);
    unsigned short u; __builtin_memcpy(&u, &h, 2); return u;
}
static __device__ __forceinline__ unsigned int pk2(float a, float b) {
    __hip_bfloat162 h = __float22bfloat162_rn(float2{a, b});
    unsigned int u; __builtin_memcpy(&u, &h, 4); return u;
}

// ---------------- W transpose + bf16: Wt[n][k], n = nt*64+nn ----------------
// Wq additionally scaled by log2(e) so attention softmax can use exp2 directly.
__global__ __launch_bounds__(256) void prep_w(
    const float* __restrict__ Wq, const float* __restrict__ Wk,
    const float* __restrict__ Wv, unsigned short* __restrict__ Wt)
{
    __shared__ float Ls[64][65];
    const int nt = blockIdx.x;           // 0..2
    const int kc = blockIdx.y;           // 0..11 (64-k chunk)
    const float* __restrict__ W = (nt == 0) ? Wq : (nt == 1) ? Wk : Wv;
    const float scl = (nt == 0) ? 1.44269504088896f : 1.0f;
    const int t = threadIdx.x;
    const int k0 = kc * 64;

#pragma unroll
    for (int it = 0; it < 16; ++it) {
        const int kk = (t >> 6) + it * 4;
        Ls[kk][t & 63] = W[(size_t)(k0 + kk) * H_DIM + (t & 63)];
    }
    __syncthreads();

#pragma unroll
    for (int it = 0; it < 4; ++it) {
        const int nl = (t >> 4) + it * 16;
        const int kl = (t & 15) * 4;
        unsigned int u[2];
        u[0] = pk2(Ls[kl + 0][nl] * scl, Ls[kl + 1][nl] * scl);
        u[1] = pk2(Ls[kl + 2][nl] * scl, Ls[kl + 3][nl] * scl);
        *(uint2*)(Wt + (size_t)(nt * 64 + nl) * E_DIM + k0 + kl) = *(uint2*)u;
    }
}

// ---------------- projection: W-in-registers, X double-buffered in LDS ----------------
// grid 256 (128-row m-tiles), 768 threads = 12 waves; wave w owns n-tile w (Q:0-3, K:4-7, V:8-11).
// NOTE: 96-VGPR persistent W file => 1 block/CU is the only viable occupancy.
// Do NOT add a min-waves launch_bounds clause: (768,6) capped VGPRs at ~85 and
// spilled the W file to scratch (FETCH 238 MB, 140 us — round-1 regression).
// Fitted cross-round budget: proj ~29.5 us vs ~16-20 us HBM floor — near-optimal; left alone.
__global__ __launch_bounds__(768) void proj_mfma(
    const float* __restrict__ X, const unsigned short* __restrict__ Wt,
    unsigned short* __restrict__ Qb, unsigned short* __restrict__ Kb,
    unsigned short* __restrict__ Vtb)
{
    __shared__ unsigned short Xs[2][16][776];   // 16-row X tile bf16, pad 776

    const int tid  = threadIdx.x;
    const int wave = tid >> 6, lane = tid & 63;
    const int row  = lane & 15, quad = lane >> 4;
    const int m0   = blockIdx.x * 128;

    // W prologue: 24 B-frags resident in registers (96 VGPRs)
    short8 bfr[24];
    {
        const unsigned short* wp = Wt + (size_t)(wave * 16 + row) * E_DIM + quad * 8;
#pragma unroll
        for (int ks = 0; ks < 24; ++ks) bfr[ks] = *(const short8*)(wp + ks * 32);
    }

    const int srow = tid & 15;
    const int sc   = tid >> 4;
    const float* __restrict__ xbase = X + (size_t)(m0 + srow) * E_DIM + sc * 16;

    float4 fx[4];
#define LDX(mt)                                                               \
    {                                                                         \
        const float* p = xbase + (size_t)(mt) * 16 * E_DIM;                   \
        fx[0] = *(const float4*)(p);     fx[1] = *(const float4*)(p + 4);     \
        fx[2] = *(const float4*)(p + 8); fx[3] = *(const float4*)(p + 12);    \
    }
#define STX(buf)                                                              \
    {                                                                         \
        unsigned int tmp[8];                                                  \
        tmp[0] = pk2(fx[0].x, fx[0].y); tmp[1] = pk2(fx[0].z, fx[0].w);       \
        tmp[2] = pk2(fx[1].x, fx[1].y); tmp[3] = pk2(fx[1].z, fx[1].w);       \
        tmp[4] = pk2(fx[2].x, fx[2].y); tmp[5] = pk2(fx[2].z, fx[2].w);       \
        tmp[6] = pk2(fx[3].x, fx[3].y); tmp[7] = pk2(fx[3].z, fx[3].w);       \
        *(int4*)&Xs[buf][srow][sc * 16]     = *(int4*)&tmp[0];                \
        *(int4*)&Xs[buf][srow][sc * 16 + 8] = *(int4*)&tmp[4];                \
    }

    // prologue: buf0 = tile 0; tile 1 loads in flight
    LDX(0); STX(0); LDX(1);
    RAWBAR();

    const int g  = wave >> 2;            // 0=Q, 1=K, 2=V
    const int h  = (wave & 3) * 16 + row;
    unsigned short* __restrict__ OQK = (g == 0) ? Qb : Kb;
    const int bb = m0 >> 12;

    int cur = 0;
    for (int mt = 0; mt < 8; ++mt) {
        // stage tile mt+1 into the idle buffer (safe: last reads of that buffer were
        // in window mt-1, sealed by the barrier), then issue loads for tile mt+2.
        if (mt < 7) STX(cur ^ 1);
        if (mt < 6) LDX(mt + 2);

        // 4 independent accumulator chains (MFMA dep-latency hiding at 3 waves/SIMD)
        floatx4 a0 = (floatx4)0.0f, a1 = (floatx4)0.0f;
        floatx4 a2 = (floatx4)0.0f, a3 = (floatx4)0.0f;
#pragma unroll
        for (int ks = 0; ks < 6; ++ks) {
            const short8 f0 = *(const short8*)&Xs[cur][row][(ks * 4 + 0) * 32 + quad * 8];
            const short8 f1 = *(const short8*)&Xs[cur][row][(ks * 4 + 1) * 32 + quad * 8];
            const short8 f2 = *(const short8*)&Xs[cur][row][(ks * 4 + 2) * 32 + quad * 8];
            const short8 f3 = *(const short8*)&Xs[cur][row][(ks * 4 + 3) * 32 + quad * 8];
            a0 = __builtin_amdgcn_mfma_f32_16x16x32_bf16(f0, bfr[ks * 4 + 0], a0, 0, 0, 0);
            a1 = __builtin_amdgcn_mfma_f32_16x16x32_bf16(f1, bfr[ks * 4 + 1], a1, 0, 0, 0);
            a2 = __builtin_amdgcn_mfma_f32_16x16x32_bf16(f2, bfr[ks * 4 + 2], a2, 0, 0, 0);
            a3 = __builtin_amdgcn_mfma_f32_16x16x32_bf16(f3, bfr[ks * 4 + 3], a3, 0, 0, 0);
        }
        floatx4 acc;
#pragma unroll
        for (int r = 0; r < 4; ++r) acc[r] = (a0[r] + a1[r]) + (a2[r] + a3[r]);

        const int mr = m0 + mt * 16 + quad * 4;
        if (g < 2) {
#pragma unroll
            for (int r = 0; r < 4; ++r)
                OQK[(size_t)(mr + r) * H_DIM + h] = bf1(acc[r]);
        } else {
            const int t0 = mr & 4095;
            unsigned int u[2];
            u[0] = pk2(acc[0], acc[1]); u[1] = pk2(acc[2], acc[3]);
            *(uint2*)(Vtb + ((size_t)bb * H_DIM + h) * T_SZ + t0) = *(uint2*)u;
        }

        RAWBAR();
        cur ^= 1;
    }
#undef LDX
#undef STX
}

// ---------------- flash attention v10: 64-row q-tiles, full-key waves, ILP2 ----------------
// Each wave owns 16 q-rows and processes ALL 64 keys of each tile as two independent
// 32-key strip chains (QK/exp2 of strip 1 overlaps PV of strip 0). vs v9: tile count,
// barrier events and staging writes HALVED; per-wave ILP doubled; the key-split is gone
// so each wave stores its own O rows directly — Oc/lc combine + syncthreads deleted.
// K rows staged PERMUTED (v9-verified): within each 32-row half,
// key r -> row ((r>>2)&1)*16 + ((r&31)>>3)*4 + (r&3), so QK output packs the
// 16x16x32 A-frag and PV runs as 4x K=32 MFMA per strip with b128 V^T reads.
// Chunks of <=12 tiles (m=1..6), no-max softmax => partials additive.
__global__ __launch_bounds__(256, 5) void attn_mfma(
    const unsigned short* __restrict__ Qb,
    const unsigned short* __restrict__ Kb,
    const unsigned short* __restrict__ Vtb,
    float* __restrict__ Opart, float* __restrict__ lpart,
    float* __restrict__ Out)
{
    // KV[0] = permuted K tile, KV[1] = V^T tile [h][key]
    __shared__ __align__(16) unsigned short KV[2][64][72];   // 18432 B

    const int lb = blockIdx.x;
    const int b  = lb & 7;                     // batch -> XCD (L2 locality)
    const int s  = lb >> 3;                    // 0..203, LPT-ordered (heavy chunks first)
    int qq, c, m;
    if (s < 24)       { m = 6; qq = 60 + s / 6;                        c = s % 6; }
    else if (s < 84)  { m = 5; const int i = s - 24;  qq = 48 + i / 5;    c = i % 5; }
    else if (s < 132) { m = 4; const int i = s - 84;  qq = 36 + (i >> 2); c = i & 3; }
    else if (s < 168) { m = 3; const int i = s - 132; qq = 24 + i / 3;    c = i % 3; }
    else if (s < 192) { m = 2; const int i = s - 168; qq = 12 + (i >> 1); c = i & 1; }
    else              { m = 1; qq = s - 192; c = 0; }
    const int ntot = qq + 1;                   // 64-key tiles for this 64-row q-tile
    const int k0t  = (c * ntot) / m;
    const int k1t  = ((c + 1) * ntot) / m;
    const int ktd  = ntot - 1;                 // diagonal tile (global index)
    const int n    = k1t - k0t;                // 1..12
    const bool split = (m > 1);

    const int tid  = threadIdx.x;
    const int wq   = tid >> 6;                 // wave owns q-rows wq*16..wq*16+15
    const int lane = tid & 63;
    const int col  = lane & 15, quad = lane >> 4;

    const size_t base = (size_t)b * T_SZ * H_DIM;
    const int q0  = qq * 64;

    // Q fragments: lane holds Q[q=col][h=quad*8..], the 16x16x32 B-operand
    short8 qf0, qf1;
    {
        const unsigned short* qp = Qb + base + (size_t)(q0 + wq * 16 + col) * H_DIM + quad * 8;
        qf0 = *(const short8*)(qp);
        qf1 = *(const short8*)(qp + 32);
    }

    floatx4 o[4];
#pragma unroll
    for (int i = 0; i < 4; ++i) o[i] = (floatx4)0.0f;
    float lp = 0.0f;                           // per-lane denom partial (q=col)

    // cooperative staging: 32B of K + 32B of V^T per thread per tile (coalesced reads).
    // K LDS row is PERMUTED (v9-verified formula).
    const int krow = tid >> 2, kcol = (tid & 3) * 16;
    const int kprow = (krow & 32) + ((krow >> 2) & 1) * 16 + ((krow & 31) >> 3) * 4 + (krow & 3);
    const unsigned short* __restrict__ Ksrc = Kb + base + (size_t)krow * H_DIM + kcol;
    const unsigned short* __restrict__ Vsrc = Vtb + ((size_t)b * H_DIM + krow) * T_SZ + kcol;

    int4 kr0, kr1, vr0, vr1;
#define LDKV(t)                                                          \
    {                                                                    \
        const unsigned short* kp = Ksrc + (size_t)(t) * 64 * H_DIM;      \
        kr0 = *(const int4*)kp; kr1 = *(const int4*)(kp + 8);            \
        const unsigned short* vp = Vsrc + (t) * 64;                      \
        vr0 = *(const int4*)vp; vr1 = *(const int4*)(vp + 8);            \
    }
#define STKV()                                                           \
    {                                                                    \
        *(int4*)&KV[0][kprow][kcol] = kr0; *(int4*)&KV[0][kprow][kcol + 8] = kr1; \
        *(int4*)&KV[1][krow][kcol] = vr0; *(int4*)&KV[1][krow][kcol + 8] = vr1; \
    }

    LDKV(k0t);
    STKV();
    if (n > 1) LDKV(k0t + 1);
    RAWBAR();

    for (int i = 0; i < n; ++i) {
        const int kt = k0t + i;

        // two independent 32-key strip chains; compiler interleaves them
#pragma unroll
        for (int j = 0; j < 2; ++j) {
            // S^T = K Q^T, A = permuted K rows: a0[r] = S[q=col][key = j*32 + quad*8 + r],
            // a1[r] = ... + 4 + r
            floatx4 a0 = (floatx4)0.0f, a1 = (floatx4)0.0f;
            __builtin_amdgcn_s_setprio(1);
            {
                const unsigned short* kp0 = &KV[0][j * 32 + col][quad * 8];
                const unsigned short* kp1 = &KV[0][j * 32 + 16 + col][quad * 8];
                a0 = __builtin_amdgcn_mfma_f32_16x16x32_bf16(*(const short8*)(kp0),      qf0, a0, 0, 0, 0);
                a1 = __builtin_amdgcn_mfma_f32_16x16x32_bf16(*(const short8*)(kp1),      qf0, a1, 0, 0, 0);
                a0 = __builtin_amdgcn_mfma_f32_16x16x32_bf16(*(const short8*)(kp0 + 32), qf1, a0, 0, 0, 0);
                a1 = __builtin_amdgcn_mfma_f32_16x16x32_bf16(*(const short8*)(kp1 + 32), qf1, a1, 0, 0, 0);
            }
            __builtin_amdgcn_s_setprio(0);

            if (kt == ktd) {                   // causal mask on diagonal tile
                const int qg = q0 + wq * 16 + col;
                const int kb = kt * 64 + j * 32 + quad * 8;
#pragma unroll
                for (int r = 0; r < 4; ++r) {
                    if (kb + r > qg)     a0[r] = -1e30f;
                    if (kb + 4 + r > qg) a1[r] = -1e30f;
                }
            }

            // no-max softmax: p = exp2(s); packs straight into the 16x16x32 A-frag
            const float p0 = exp2f(a0[0]), p1 = exp2f(a0[1]), p2 = exp2f(a0[2]), p3 = exp2f(a0[3]);
            const float p4 = exp2f(a1[0]), p5 = exp2f(a1[1]), p6 = exp2f(a1[2]), p7 = exp2f(a1[3]);
            lp += ((p0 + p1) + (p2 + p3)) + ((p4 + p5) + (p6 + p7));
            unsigned int u0, u1, u2, u3;
            __asm__("v_cvt_pk_bf16_f32 %0, %1, %2" : "=v"(u0) : "v"(p0), "v"(p1));
            __asm__("v_cvt_pk_bf16_f32 %0, %1, %2" : "=v"(u1) : "v"(p2), "v"(p3));
            __asm__("v_cvt_pk_bf16_f32 %0, %1, %2" : "=v"(u2) : "v"(p4), "v"(p5));
            __asm__("v_cvt_pk_bf16_f32 %0, %1, %2" : "=v"(u3) : "v"(p6), "v"(p7));
            union { unsigned int u[4]; short8 v; } pu;
            pu.u[0] = u0; pu.u[1] = u1; pu.u[2] = u2; pu.u[3] = u3;
            const short8 pa = pu.v;

            // O += P V over this strip: 4x K=32 MFMA, B = V^T b128 slices
            __builtin_amdgcn_s_setprio(1);
#pragma unroll
            for (int d = 0; d < 4; ++d) {
                const short8 vb = *(const short8*)(&KV[1][d * 16 + col][j * 32 + quad * 8]);
                o[d] = __builtin_amdgcn_mfma_f32_16x16x32_bf16(pa, vb, o[d], 0, 0, 0);
            }
            __builtin_amdgcn_s_setprio(0);
        }

        RAWBAR();                              // all waves done reading KV
        if (i + 1 < n) {
            STKV();                            // vmcnt wait: loads issued a full iter ago
            if (i + 2 < n) LDKV(kt + 2);
        }
        RAWBAR();
    }

    // denom: reduce lp across the 4 quads (same col); fetch per-o-row values in-wave
    lp += __shfl_xor(lp, 16);
    lp += __shfl_xor(lp, 32);
    float lr[4];
#pragma unroll
    for (int r = 0; r < 4; ++r) lr[r] = __shfl(lp, quad * 4 + r);

    // o[d][r] = O[q-local = quad*4 + r][h = d*16 + col] for q-rows wq*16 + quad*4 + r
    if (!split) {
        float* op = Out + base + (size_t)(q0 + wq * 16 + quad * 4) * H_DIM;
#pragma unroll
        for (int r = 0; r < 4; ++r) {
            const float inv = 1.0f / lr[r];
#pragma unroll
            for (int d = 0; d < 4; ++d)
                op[(size_t)r * H_DIM + d * 16 + col] = o[d][r] * inv;
        }
    } else {
        const int pidx = (b * 64 + qq) * 6 + c;
        float* op = Opart + ((size_t)pidx * 64 + wq * 16 + quad * 4) * 64;
#pragma unroll
        for (int r = 0; r < 4; ++r)
#pragma unroll
            for (int d = 0; d < 4; ++d)
                op[(size_t)r * 64 + d * 16 + col] = o[d][r];
        if (quad == 0) lpart[pidx * 64 + wq * 16 + col] = lp;
    }
#undef LDKV
#undef STKV
}

// ---------------- split-K combine: 64-row q-tiles qq>=12, m in {2..6} partials ----------------
__global__ __launch_bounds__(256) void attn_combine(
    const float* __restrict__ Opart, const float* __restrict__ lpart,
    float* __restrict__ Out)
{
    const int qq  = 12 + blockIdx.x;          // 12..63
    const int b   = blockIdx.y;               // 0..7
    const int m   = (qq + 12) / 12;           // ceil((qq+1)/12) in 2..6
    const int tid = threadIdx.x;
    const int orow = tid >> 2;                // 0..63
    const int d0   = (tid & 3) * 16;
    const int p0   = (b * 64 + qq) * 6;

    float4 a0 = {0.f,0.f,0.f,0.f}, a1 = {0.f,0.f,0.f,0.f};
    float4 a2 = {0.f,0.f,0.f,0.f}, a3 = {0.f,0.f,0.f,0.f};
    float l = 0.0f;
    for (int j = 0; j < m; ++j) {
        const float* P = Opart + ((size_t)(p0 + j) * 64 + orow) * 64 + d0;
        const float4 b0 = *(const float4*)(P);
        const float4 b1 = *(const float4*)(P + 4);
        const float4 b2 = *(const float4*)(P + 8);
        const float4 b3 = *(const float4*)(P + 12);
        a0.x += b0.x; a0.y += b0.y; a0.z += b0.z; a0.w += b0.w;
        a1.x += b1.x; a1.y += b1.y; a1.z += b1.z; a1.w += b1.w;
        a2.x += b2.x; a2.y += b2.y; a2.z += b2.z; a2.w += b2.w;
        a3.x += b3.x; a3.y += b3.y; a3.z += b3.z; a3.w += b3.w;
        l += lpart[(p0 + j) * 64 + orow];
    }
    const float inv = 1.0f / l;
    a0.x *= inv; a0.y *= inv; a0.z *= inv; a0.w *= inv;
    a1.x *= inv; a1.y *= inv; a1.z *= inv; a1.w *= inv;
    a2.x *= inv; a2.y *= inv; a2.z *= inv; a2.w *= inv;
    a3.x *= inv; a3.y *= inv; a3.z *= inv; a3.w *= inv;

    float* op = Out + ((size_t)b * T_SZ + qq * 64 + orow) * H_DIM + d0;
    *(float4*)(op)      = a0;
    *(float4*)(op + 4)  = a1;
    *(float4*)(op + 8)  = a2;
    *(float4*)(op + 12) = a3;
}

extern "C" void kernel_launch(void* const* d_in, const int* in_sizes, int n_in,
                              void* d_out, int out_size, void* d_ws, size_t ws_size,
                              hipStream_t stream) {
    const float* X  = (const float*)d_in[0];
    const float* Wq = (const float*)d_in[1];
    const float* Wk = (const float*)d_in[2];
    const float* Wv = (const float*)d_in[3];

    unsigned short* Wt  = (unsigned short*)d_ws;            // 192*768 bf16
    unsigned short* Qb  = Wt + (size_t)192 * E_DIM;
    unsigned short* Kb  = Qb + (size_t)BT * H_DIM;
    unsigned short* Vtb = Kb + (size_t)BT * H_DIM;          // V transposed [b][h][t]
    float* Opart = (float*)(Vtb + (size_t)BT * H_DIM);      // [3072][64][64] f32 = 50.3 MB
    float* lpart = Opart + (size_t)3072 * 64 * 64;          // [3072][64] f32

    prep_w<<<dim3(3, 12), 256, 0, stream>>>(Wq, Wk, Wv, Wt);
    proj_mfma<<<256, 768, 0, stream>>>(X, Wt, Qb, Kb, Vtb);
    attn_mfma<<<1632, 256, 0, stream>>>(Qb, Kb, Vtb, Opart, lpart, (float*)d_out);
    attn_combine<<<dim3(52, 8), 256, 0, stream>>>(Opart, lpart, (float*)d_out);
}